// Round 12
// baseline (204.421 us; speedup 1.0000x reference)
//
#include <hip/hip_runtime.h>
#include <stdint.h>

#define NTOK 4096
#define NH 12
#define HDIM 64
#define DMODEL 768
#define D3 2304

typedef __attribute__((ext_vector_type(8))) __bf16 bf16x8;
typedef __attribute__((ext_vector_type(4))) float f32x4;
typedef __attribute__((ext_vector_type(4))) unsigned int u32x4;

#define MFMA(a, b, c) __builtin_amdgcn_mfma_f32_16x16x32_bf16((a), (b), (c), 0, 0, 0)

// round-half-up bf16 (0.5-ulp bound, same as RNE)
__device__ __forceinline__ uint16_t f2bf(float f) {
  uint32_t u = __builtin_bit_cast(uint32_t, f) + 0x8000u;
  return (uint16_t)(u >> 16);
}
// pack two floats -> two bf16 in one dword, round-half-up: 2 adds + 1 v_perm
__device__ __forceinline__ uint32_t packrd(float a, float b) {
  uint32_t ua = __builtin_bit_cast(uint32_t, a) + 0x8000u;
  uint32_t ub = __builtin_bit_cast(uint32_t, b) + 0x8000u;
  return __builtin_amdgcn_perm(ub, ua, 0x07060302u);
}
// pack two floats -> two bf16, TRUNCATE (1 op). P only: bias cancels in O/l.
__device__ __forceinline__ uint32_t packtr(float a, float b) {
  return __builtin_amdgcn_perm(__builtin_bit_cast(uint32_t, b), __builtin_bit_cast(uint32_t, a),
                               0x07060302u);
}
__device__ __forceinline__ float bf2f(uint16_t u) {
  uint32_t v = ((uint32_t)u) << 16;
  return __builtin_bit_cast(float, v);
}
// async global->LDS, 16B per lane; lds dest = wave-uniform base + lane*16
__device__ __forceinline__ void gld_lds16(const uint16_t* g, uint16_t* l) {
  __builtin_amdgcn_global_load_lds((const __attribute__((address_space(1))) void*)g,
                                   (__attribute__((address_space(3))) void*)l, 16, 0, 0);
}

// ---------------- cast hidden fp32 -> bf16, plus cs4 table build ----------------
// blocks [0, n4/256): cast. blocks beyond: cs4[n][d0] = (cos_d, sin_d, cos_{d+32}, sin_{d+32}).
__global__ void va_cast_cs4(const float* __restrict__ in, uint16_t* __restrict__ out,
                            const float* __restrict__ cosb, const float* __restrict__ sinb,
                            float4* __restrict__ cs4, int n4) {
  int i = blockIdx.x * 256 + threadIdx.x;
  if (i < n4) {
    float4 v = ((const float4*)in)[i];
    ((uint2*)out)[i] = make_uint2(packrd(v.x, v.y), packrd(v.z, v.w));
    return;
  }
  int idx = i - n4;  // 0 .. NTOK*32-1
  if (idx >= NTOK * 32) return;
  int n = idx >> 5, d0 = idx & 31;
  cs4[idx] = make_float4(cosb[n * HDIM + d0], sinb[n * HDIM + d0], cosb[n * HDIM + d0 + 32],
                         sinb[n * HDIM + d0 + 32]);
}

// ---------------- transpose + cast: W[K][N] fp32 -> Wt[N][K] bf16 ----------------
__global__ void va_transpose_cast(const float* __restrict__ W, uint16_t* __restrict__ Wt,
                                  int K, int Ncols) {
  __shared__ uint16_t tile[32][36];
  const int t = threadIdx.x;
  const int k0 = blockIdx.y * 32, n0 = blockIdx.x * 32;
  {
    int i = t >> 3, j = (t & 7) * 4;
    float4 v = *(const float4*)(W + (size_t)(k0 + i) * Ncols + n0 + j);
    tile[i][j + 0] = f2bf(v.x);
    tile[i][j + 1] = f2bf(v.y);
    tile[i][j + 2] = f2bf(v.z);
    tile[i][j + 3] = f2bf(v.w);
  }
  __syncthreads();
  {
    int c = t >> 3, kk = (t & 7) * 4;
    uint32_t lo = (uint32_t)tile[kk + 0][c] | ((uint32_t)tile[kk + 1][c] << 16);
    uint32_t hi = (uint32_t)tile[kk + 2][c] | ((uint32_t)tile[kk + 3][c] << 16);
    *(uint2*)(Wt + (size_t)(n0 + c) * K + k0 + kk) = make_uint2(lo, hi);
  }
}

// ---------------- fused QKV GEMM + RoPE + V-plane-permute ----------------
// m97 structure (128x128 tile, BK=32). Epilogue by column-block type:
//   Q/K: RoPE in-register via packed cs4 float4 loads (1 dwordx4 per rope pair vs 4 scalar);
//   stored d-INTERLEAVED pair layout [h][n][2*(d&31)+(d>>5)] (shared d-perm is free in QK^T).
//   V: plane-permuted store for the free-P PV contraction.
__global__ __launch_bounds__(256) void va_gemm_qkv(const uint16_t* __restrict__ A,
                                                   const uint16_t* __restrict__ Bt,
                                                   const float* __restrict__ bias,
                                                   const float4* __restrict__ cs4,
                                                   uint16_t* __restrict__ Qg,
                                                   uint16_t* __restrict__ Kg,
                                                   uint16_t* __restrict__ Vtg) {
  __shared__ uint16_t As[128 * 32];
  __shared__ uint16_t Bs[128 * 32];
  const int t = threadIdx.x;
  const int w = t >> 6, ln = t & 63, quad = ln >> 4, l15 = ln & 15;
  const int m0 = blockIdx.y * 128, n0 = blockIdx.x * 128;
  const int wm = (w & 1) * 64, wn = (w >> 1) * 64;
  const int srow = t >> 2, scol = (t & 3) * 8;
  f32x4 acc[4][4] = {};
  for (int kk = 0; kk < DMODEL; kk += 32) {
#pragma unroll
    for (int p = 0; p < 2; ++p) {
      gld_lds16(A + (size_t)(m0 + p * 64 + srow) * DMODEL + kk + scol,
                As + (p * 64 + w * 16) * 32);
      gld_lds16(Bt + (size_t)(n0 + p * 64 + srow) * DMODEL + kk + scol,
                Bs + (p * 64 + w * 16) * 32);
    }
    __syncthreads();
    bf16x8 af[4], bfr[4];
#pragma unroll
    for (int i = 0; i < 4; ++i) {
      af[i] = *(const bf16x8*)(As + (wm + i * 16 + l15) * 32 + quad * 8);
      bfr[i] = *(const bf16x8*)(Bs + (wn + i * 16 + l15) * 32 + quad * 8);
    }
#pragma unroll
    for (int i = 0; i < 4; ++i)
#pragma unroll
      for (int j = 0; j < 4; ++j) acc[i][j] = MFMA(af[i], bfr[j], acc[i][j]);
    __syncthreads();
  }
  const int col0 = n0 + wn;          // multiple of 64
  const int type = col0 / DMODEL;    // 0=Q 1=K 2=V
  const int h = (col0 % DMODEL) / HDIM;
  if (type < 2) {
    const float sc = (type == 0) ? (0.125f * 1.4426950408889634f) : 1.0f;
    uint16_t* dst = (type == 0 ? Qg : Kg) + (size_t)h * NTOK * HDIM;
#pragma unroll
    for (int j = 0; j < 2; ++j) {
      const int d = j * 16 + l15;  // 0..31
      const float blo = bias[col0 + d], bhi = bias[col0 + d + 32];
#pragma unroll
      for (int i = 0; i < 4; ++i) {
        const int row0 = m0 + wm + i * 16 + quad * 4;
#pragma unroll
        for (int rg = 0; rg < 4; ++rg) {
          const int n = row0 + rg;
          const float a = acc[i][j][rg] + blo;
          const float b = acc[i][j + 2][rg] + bhi;
          const float4 cs = cs4[n * 32 + d];
          *(uint32_t*)(dst + (size_t)n * HDIM + 2 * d) =
              packrd((a * cs.x - b * cs.y) * sc, (b * cs.z + a * cs.w) * sc);
        }
      }
    }
  } else {
    const int win = (m0 + wm) >> 6;
#pragma unroll
    for (int i = 0; i < 4; ++i) {
      const int H = i & 1, hb = (i >> 1) & 1;
      const int colp = win * 32 + quad * 8 + hb * 4;
#pragma unroll
      for (int j = 0; j < 4; ++j) {
        const int d = j * 16 + l15;
        const float bb = bias[col0 + d];
        uint32_t u0 = packrd(acc[i][j][0] + bb, acc[i][j][1] + bb);
        uint32_t u1 = packrd(acc[i][j][2] + bb, acc[i][j][3] + bb);
        *(uint2*)(Vtg + (((size_t)H * NH + h) * HDIM + d) * 2048 + colp) = make_uint2(u0, u1);
      }
    }
  }
}

// ---------------- fused combine + proj GEMM: out = ((Op0+Op1)*inv) @ Wpt^T + bias ----------
// A-tile staged via VGPR round-trip: uint4 loads of both split planes (prefetched one k-iter
// ahead so they overlap MFMA), normalize by per-row inv[h], pack, ds_write_b128 to the exact
// gld_lds16 LDS layout (base + lane*16B). B stays async gld_lds16.
__global__ __launch_bounds__(256) void va_gemm_proj(const uint16_t* __restrict__ Opb,
                                                    const float* __restrict__ Lp,
                                                    const uint16_t* __restrict__ Bt,
                                                    const float* __restrict__ bias,
                                                    float* __restrict__ C) {
  __shared__ uint16_t As[64 * 32];
  __shared__ uint16_t Bs[128 * 32];
  const int t = threadIdx.x;
  const int w = t >> 6, ln = t & 63, quad = ln >> 4, l15 = ln & 15;
  const int m0 = blockIdx.y * 64, n0 = blockIdx.x * 128;
  const int wn = w * 32;
  const int srow = t >> 2, scol = (t & 3) * 8;
  const int n = m0 + srow;  // A row this lane stages
  float inv[NH];
#pragma unroll
  for (int hh = 0; hh < NH; ++hh)
    inv[hh] = 1.0f / (Lp[(size_t)hh * NTOK + n] + Lp[((size_t)NH + hh) * NTOK + n]);
  const uint16_t* pa = Opb + (size_t)n * DMODEL + scol;
  const uint16_t* pb = pa + (size_t)NTOK * DMODEL;
  uint16_t ua[8], ub[8];
  *(uint4*)ua = *(const uint4*)pa;
  *(uint4*)ub = *(const uint4*)pb;
  f32x4 acc[4][2] = {};
  for (int kk = 0; kk < DMODEL; kk += 32) {
    {  // normalize current A chunk and write to LDS (gld_lds16-identical layout)
      const float iv = inv[(kk + scol) >> 6];
      uint32_t o[4];
#pragma unroll
      for (int j = 0; j < 8; j += 2)
        o[j >> 1] = packrd((bf2f(ua[j]) + bf2f(ub[j])) * iv,
                           (bf2f(ua[j + 1]) + bf2f(ub[j + 1])) * iv);
      *(uint4*)(As + w * 16 * 32 + ln * 8) = *(uint4*)o;
    }
#pragma unroll
    for (int p = 0; p < 2; ++p)
      gld_lds16(Bt + (size_t)(n0 + p * 64 + srow) * DMODEL + kk + scol,
                Bs + (p * 64 + w * 16) * 32);
    if (kk + 32 < DMODEL) {  // prefetch next A chunk (overlaps MFMA below)
      *(uint4*)ua = *(const uint4*)(pa + kk + 32);
      *(uint4*)ub = *(const uint4*)(pb + kk + 32);
    }
    __syncthreads();
    bf16x8 af[4], bfr[2];
#pragma unroll
    for (int i = 0; i < 4; ++i) af[i] = *(const bf16x8*)(As + (i * 16 + l15) * 32 + quad * 8);
#pragma unroll
    for (int j = 0; j < 2; ++j)
      bfr[j] = *(const bf16x8*)(Bs + (wn + j * 16 + l15) * 32 + quad * 8);
#pragma unroll
    for (int i = 0; i < 4; ++i)
#pragma unroll
      for (int j = 0; j < 2; ++j) acc[i][j] = MFMA(af[i], bfr[j], acc[i][j]);
    __syncthreads();
  }
#pragma unroll
  for (int i = 0; i < 4; ++i) {
    int row = m0 + i * 16 + quad * 4;
#pragma unroll
    for (int j = 0; j < 2; ++j) {
      int col = n0 + wn + j * 16 + l15;
      float b = bias[col];
#pragma unroll
      for (int rg = 0; rg < 4; ++rg) C[(size_t)(row + rg) * DMODEL + col] = acc[i][j][rg] + b;
    }
  }
}

// ---------------- Flash attention v11 (unchanged structure) ----------------
__global__ __launch_bounds__(256, 3) void va_flash11(const uint16_t* __restrict__ Qg,
                                                     const uint16_t* __restrict__ Kg,
                                                     const uint16_t* __restrict__ Vtg,
                                                     uint16_t* __restrict__ Opb,
                                                     float* __restrict__ Lp) {
  __shared__ uint16_t Ks[2][2][64 * 32];  // [dbuf][d-half][64 keys x 32 d]
  __shared__ uint16_t Vs[2][2][64 * 32];  // [dbuf][key-plane H][64 d x 32 permuted keys]
  const int t = threadIdx.x;
  const int w = t >> 6, ln = t & 63, quad = ln >> 4, l15 = ln & 15;
  const int h = blockIdx.y;
  const int qb = blockIdx.x & 31, ks = blockIdx.x >> 5;
  const int q0 = qb * 128, key0 = ks * 2048;

  bf16x8 qf[2][2];
#pragma unroll
  for (int s = 0; s < 2; ++s)
#pragma unroll
    for (int c = 0; c < 2; ++c)
      qf[s][c] = *(const bf16x8*)(Qg + ((size_t)h * NTOK + q0 + w * 32 + s * 16 + l15) * HDIM +
                                  c * 32 + quad * 8);
  const u32x4 onesu = {0x3F803F80u, 0x3F803F80u, 0x3F803F80u, 0x3F803F80u};
  const bf16x8 vones = __builtin_bit_cast(bf16x8, onesu);
  f32x4 o[2][4] = {};
  f32x4 ol[2] = {};
  const uint16_t* Kst =
      Kg + ((size_t)h * NTOK + key0 + w * 16 + (ln >> 2)) * HDIM + (ln & 3) * 8;
  const uint16_t* Vst0 =
      Vtg + (((size_t)0 * NH + h) * HDIM + w * 16 + (ln >> 2)) * 2048 + ks * 1024 + (ln & 3) * 8;
  const uint16_t* Vst1 =
      Vtg + (((size_t)1 * NH + h) * HDIM + w * 16 + (ln >> 2)) * 2048 + ks * 1024 + (ln & 3) * 8;

  gld_lds16(Kst, &Ks[0][0][w * 16 * 32]);
  gld_lds16(Kst + 32, &Ks[0][1][w * 16 * 32]);
  gld_lds16(Vst0, &Vs[0][0][w * 16 * 32]);
  gld_lds16(Vst1, &Vs[0][1][w * 16 * 32]);

  for (int kt = 0; kt < 32; ++kt) {
    __syncthreads();
    const int cur = kt & 1;
    if (kt < 31) {
      Kst += 64 * HDIM;
      Vst0 += 32;
      Vst1 += 32;
      gld_lds16(Kst, &Ks[cur ^ 1][0][w * 16 * 32]);
      gld_lds16(Kst + 32, &Ks[cur ^ 1][1][w * 16 * 32]);
      gld_lds16(Vst0, &Vs[cur ^ 1][0][w * 16 * 32]);
      gld_lds16(Vst1, &Vs[cur ^ 1][1][w * 16 * 32]);
    }
    f32x4 st[2][4];
#pragma unroll
    for (int mt = 0; mt < 4; ++mt) {
      bf16x8 ka0 = *(const bf16x8*)(&Ks[cur][0][(mt * 16 + l15) * 32 + quad * 8]);
      bf16x8 ka1 = *(const bf16x8*)(&Ks[cur][1][(mt * 16 + l15) * 32 + quad * 8]);
#pragma unroll
      for (int s = 0; s < 2; ++s) {
        f32x4 z = {};
        z = MFMA(ka0, qf[s][0], z);
        st[s][mt] = MFMA(ka1, qf[s][1], z);
      }
    }
    bf16x8 vf[4][2];
#pragma unroll
    for (int dt = 0; dt < 4; ++dt)
#pragma unroll
      for (int H = 0; H < 2; ++H)
        vf[dt][H] = *(const bf16x8*)(&Vs[cur][H][(dt * 16 + l15) * 32 + quad * 8]);
#pragma unroll
    for (int s = 0; s < 2; ++s) {
      uint32_t Ppk[4][2];
#pragma unroll
      for (int mt = 0; mt < 4; ++mt) {
        float p0 = __builtin_amdgcn_exp2f(st[s][mt][0]);
        float p1 = __builtin_amdgcn_exp2f(st[s][mt][1]);
        float p2 = __builtin_amdgcn_exp2f(st[s][mt][2]);
        float p3 = __builtin_amdgcn_exp2f(st[s][mt][3]);
        Ppk[mt][0] = packtr(p0, p1);
        Ppk[mt][1] = packtr(p2, p3);
      }
#pragma unroll
      for (int H = 0; H < 2; ++H) {
        u32x4 d = {Ppk[H][0], Ppk[H][1], Ppk[H + 2][0], Ppk[H + 2][1]};
        bf16x8 pf = __builtin_bit_cast(bf16x8, d);
#pragma unroll
        for (int dt = 0; dt < 4; ++dt) o[s][dt] = MFMA(vf[dt][H], pf, o[s][dt]);
        ol[s] = MFMA(vones, pf, ol[s]);
      }
    }
  }
  // epilogue: row-major unnormalized O (bf16, packed uint2) + per-query l (fp32)
#pragma unroll
  for (int s = 0; s < 2; ++s) {
    const int q = q0 + w * 32 + s * 16 + l15;
    uint16_t* row = Opb + ((size_t)ks * NTOK + q) * DMODEL + h * HDIM + quad * 4;
#pragma unroll
    for (int dt = 0; dt < 4; ++dt) {
      uint32_t u0 = packrd(o[s][dt][0], o[s][dt][1]);
      uint32_t u1 = packrd(o[s][dt][2], o[s][dt][3]);
      *(uint2*)(row + dt * 16) = make_uint2(u0, u1);
    }
    if (quad == 0) Lp[(size_t)(ks * NH + h) * NTOK + q] = ol[s][0];
  }
}

extern "C" void kernel_launch(void* const* d_in, const int* in_sizes, int n_in, void* d_out,
                              int out_size, void* d_ws, size_t ws_size, hipStream_t stream) {
  (void)in_sizes; (void)n_in; (void)out_size; (void)ws_size;
  const float* hidden = (const float*)d_in[0];
  const float* cosb = (const float*)d_in[1];
  const float* sinb = (const float*)d_in[2];
  const float* qkv_w = (const float*)d_in[3];
  const float* qkv_b = (const float*)d_in[4];
  const float* proj_w = (const float*)d_in[5];
  const float* proj_b = (const float*)d_in[6];
  float* out = (float*)d_out;

  char* ws = (char*)d_ws;
  size_t off = 0;
  auto alloc = [&](size_t bytes) {
    void* p = ws + off;
    off += (bytes + 255) & ~(size_t)255;
    return p;
  };
  uint16_t* Abf = (uint16_t*)alloc((size_t)NTOK * DMODEL * 2);
  uint16_t* Wqt = (uint16_t*)alloc((size_t)D3 * DMODEL * 2);
  uint16_t* Wpt = (uint16_t*)alloc((size_t)DMODEL * DMODEL * 2);
  float4* cs4 = (float4*)alloc((size_t)NTOK * 32 * 16);
  uint16_t* Qb = (uint16_t*)alloc((size_t)NH * NTOK * HDIM * 2);
  uint16_t* Kb = (uint16_t*)alloc((size_t)NH * NTOK * HDIM * 2);
  uint16_t* Vtb = (uint16_t*)alloc((size_t)2 * NH * HDIM * 2048 * 2);  // split planes
  uint16_t* Opb = (uint16_t*)alloc((size_t)2 * NTOK * DMODEL * 2);     // row-major per split
  float* Lp = (float*)alloc((size_t)2 * NH * NTOK * 4);

  const int n4 = NTOK * DMODEL / 4;
  va_cast_cs4<<<(n4 + NTOK * 32 + 255) / 256, 256, 0, stream>>>(hidden, Abf, cosb, sinb, cs4,
                                                                n4);
  va_transpose_cast<<<dim3(D3 / 32, DMODEL / 32), 256, 0, stream>>>(qkv_w, Wqt, DMODEL, D3);
  va_transpose_cast<<<dim3(DMODEL / 32, DMODEL / 32), 256, 0, stream>>>(proj_w, Wpt, DMODEL,
                                                                        DMODEL);
  va_gemm_qkv<<<dim3(D3 / 128, NTOK / 128), 256, 0, stream>>>(Abf, Wqt, qkv_b, cs4, Qb, Kb,
                                                              Vtb);
  va_flash11<<<dim3(64, NH), 256, 0, stream>>>(Qb, Kb, Vtb, Opb, Lp);
  va_gemm_proj<<<dim3(DMODEL / 128, NTOK / 64), 256, 0, stream>>>(Opb, Lp, Wpt, proj_b, out);
}